// Round 1
// baseline (179.179 us; speedup 1.0000x reference)
//
#include <hip/hip_runtime.h>
#include <math.h>

#define BATCH  8
#define SEQ    8192
#define DMODEL 256
#define DSTATE 2

// ---------------------------------------------------------------------------
// Layouts:
//   x  : [B][T][D] fp32
//   params (log_a_mag, a_phase, B_re, B_im, C_re, C_im): [D][S] fp32 (S=2)
//   E / Hin workspace: [B][C][64][16] floats
//       per (b, c): 64 lanes (d4 = d/4) x 16 floats = {j=0..3: (s0_re, s0_im,
//       s1_re, s1_im)} -> one float4 per j.
//   y  : [B][T][D] fp32
// Recurrence: h[t] = a * h[t-1] + Bc * x[t],  a = e^{lm} (cos ph + i sin ph)
// y[t,d] = sum_s Re(C * h) + D_diag * x
// ---------------------------------------------------------------------------

// Kernel 1: per-chunk local end state (zero initial condition).
// grid = BATCH * C blocks, 64 threads. block -> (b, c); lane -> d4 (4 d's).
__global__ void ssm_chunk_state(const float* __restrict__ x,
                                const float* __restrict__ lam,
                                const float* __restrict__ aph,
                                const float* __restrict__ Bre,
                                const float* __restrict__ Bim,
                                float* __restrict__ E,
                                int C, int L) {
    const int lane = threadIdx.x;           // 0..63
    const int bid  = blockIdx.x;            // b*C + c
    const int b = bid / C;
    const int c = bid % C;
    const int d0 = lane * 4;

    float ar[4][2], ai[4][2], br[4][2], bi[4][2];
#pragma unroll
    for (int j = 0; j < 4; ++j) {
        const int d = d0 + j;
#pragma unroll
        for (int s = 0; s < 2; ++s) {
            const float lm = lam[d * 2 + s];
            const float ph = aph[d * 2 + s];
            const float m  = expf(lm);
            ar[j][s] = m * cosf(ph);
            ai[j][s] = m * sinf(ph);
            br[j][s] = Bre[d * 2 + s];
            bi[j][s] = Bim[d * 2 + s];
        }
    }

    float hr[4][2] = {}, hi[4][2] = {};

    const float* xp = x + ((size_t)b * SEQ + (size_t)c * L) * DMODEL + d0;
#pragma unroll 4
    for (int t = 0; t < L; ++t) {
        const float4 xv = *reinterpret_cast<const float4*>(xp + (size_t)t * DMODEL);
        const float xj[4] = {xv.x, xv.y, xv.z, xv.w};
#pragma unroll
        for (int j = 0; j < 4; ++j) {
#pragma unroll
            for (int s = 0; s < 2; ++s) {
                const float nr = fmaf(ar[j][s], hr[j][s],
                                 fmaf(-ai[j][s], hi[j][s], br[j][s] * xj[j]));
                const float ni = fmaf(ar[j][s], hi[j][s],
                                 fmaf( ai[j][s], hr[j][s], bi[j][s] * xj[j]));
                hr[j][s] = nr;
                hi[j][s] = ni;
            }
        }
    }

    float* ep = E + ((size_t)(b * C + c) * 64 + lane) * 16;
#pragma unroll
    for (int j = 0; j < 4; ++j) {
        float4 v;
        v.x = hr[j][0]; v.y = hi[j][0];
        v.z = hr[j][1]; v.w = hi[j][1];
        reinterpret_cast<float4*>(ep)[j] = v;
    }
}

// Kernel 2: scan over chunks. 4096 threads, one per (b, d, s).
// Hin[b][c] = state entering chunk c (i.e. end state of chunk c-1).
__global__ void ssm_chunk_scan(const float* __restrict__ E,
                               float* __restrict__ Hin,
                               const float* __restrict__ lam,
                               const float* __restrict__ aph,
                               int C, int L) {
    const int g = blockIdx.x * blockDim.x + threadIdx.x;   // 0..4095
    const int b = g >> 9;            // 512 slots per batch: 64 d4 * 4 j * 2 s
    const int r = g & 511;
    const int d4 = r >> 3;
    const int j  = (r >> 1) & 3;
    const int s  = r & 1;
    const int d  = d4 * 4 + j;

    // a^L in double: coherent phase-rounding over C steps stays negligible.
    const double l = (double)lam[d * 2 + s] * (double)L;
    const double p = (double)aph[d * 2 + s] * (double)L;
    const double m = exp(l);
    const float aLr = (float)(m * cos(p));
    const float aLi = (float)(m * sin(p));

    const size_t base = (size_t)b * C * 1024 + (size_t)r * 2;

    float hr = 0.f, hi = 0.f;
#pragma unroll 4
    for (int c = 0; c < C; ++c) {
        const size_t off = base + (size_t)c * 1024;
        const float2 e = *reinterpret_cast<const float2*>(E + off);
        *reinterpret_cast<float2*>(Hin + off) = make_float2(hr, hi);
        const float nr = fmaf(aLr, hr, fmaf(-aLi, hi, e.x));
        const float ni = fmaf(aLr, hi, fmaf( aLi, hr, e.y));
        hr = nr;
        hi = ni;
    }
}

// Kernel 3: re-run local recurrence seeded from Hin; fuse output projection.
__global__ void ssm_output(const float* __restrict__ x,
                           const float* __restrict__ lam,
                           const float* __restrict__ aph,
                           const float* __restrict__ Bre,
                           const float* __restrict__ Bim,
                           const float* __restrict__ Cre,
                           const float* __restrict__ Cim,
                           const float* __restrict__ Dd,
                           const float* __restrict__ Hin,
                           float* __restrict__ y,
                           int C, int L) {
    const int lane = threadIdx.x;
    const int bid  = blockIdx.x;
    const int b = bid / C;
    const int c = bid % C;
    const int d0 = lane * 4;

    float ar[4][2], ai[4][2], br[4][2], bi[4][2], cr[4][2], ci[4][2], dd[4];
#pragma unroll
    for (int j = 0; j < 4; ++j) {
        const int d = d0 + j;
        dd[j] = Dd[d];
#pragma unroll
        for (int s = 0; s < 2; ++s) {
            const float lm = lam[d * 2 + s];
            const float ph = aph[d * 2 + s];
            const float m  = expf(lm);
            ar[j][s] = m * cosf(ph);
            ai[j][s] = m * sinf(ph);
            br[j][s] = Bre[d * 2 + s];
            bi[j][s] = Bim[d * 2 + s];
            cr[j][s] = Cre[d * 2 + s];
            ci[j][s] = Cim[d * 2 + s];
        }
    }

    float hr[4][2], hi[4][2];
    const float* hp = Hin + ((size_t)(b * C + c) * 64 + lane) * 16;
#pragma unroll
    for (int j = 0; j < 4; ++j) {
        const float4 v = reinterpret_cast<const float4*>(hp)[j];
        hr[j][0] = v.x; hi[j][0] = v.y;
        hr[j][1] = v.z; hi[j][1] = v.w;
    }

    const size_t tbase = ((size_t)b * SEQ + (size_t)c * L) * DMODEL + d0;
    const float* xp = x + tbase;
    float* yp = y + tbase;
#pragma unroll 4
    for (int t = 0; t < L; ++t) {
        const float4 xv = *reinterpret_cast<const float4*>(xp + (size_t)t * DMODEL);
        const float xj[4] = {xv.x, xv.y, xv.z, xv.w};
        float yj[4];
#pragma unroll
        for (int j = 0; j < 4; ++j) {
            float acc = dd[j] * xj[j];
#pragma unroll
            for (int s = 0; s < 2; ++s) {
                const float nr = fmaf(ar[j][s], hr[j][s],
                                 fmaf(-ai[j][s], hi[j][s], br[j][s] * xj[j]));
                const float ni = fmaf(ar[j][s], hi[j][s],
                                 fmaf( ai[j][s], hr[j][s], bi[j][s] * xj[j]));
                hr[j][s] = nr;
                hi[j][s] = ni;
                acc = fmaf(cr[j][s], nr, acc);
                acc = fmaf(-ci[j][s], ni, acc);
            }
            yj[j] = acc;
        }
        float4 yv;
        yv.x = yj[0]; yv.y = yj[1]; yv.z = yj[2]; yv.w = yj[3];
        *reinterpret_cast<float4*>(yp + (size_t)t * DMODEL) = yv;
    }
}

extern "C" void kernel_launch(void* const* d_in, const int* in_sizes, int n_in,
                              void* d_out, int out_size, void* d_ws, size_t ws_size,
                              hipStream_t stream) {
    const float* x   = (const float*)d_in[0];
    const float* lam = (const float*)d_in[1];
    const float* aph = (const float*)d_in[2];
    const float* Bre = (const float*)d_in[3];
    const float* Bim = (const float*)d_in[4];
    const float* Cre = (const float*)d_in[5];
    const float* Cim = (const float*)d_in[6];
    const float* Dd  = (const float*)d_in[7];
    float* y = (float*)d_out;

    // Pick the largest chunk count whose E+Hin workspace fits.
    int C = 256;
    while (C > 8 && ws_size < (size_t)2 * BATCH * C * 1024 * sizeof(float)) C >>= 1;
    const int L = SEQ / C;

    float* E   = (float*)d_ws;
    float* Hin = E + (size_t)BATCH * C * 1024;

    ssm_chunk_state<<<BATCH * C, 64, 0, stream>>>(x, lam, aph, Bre, Bim, E, C, L);
    ssm_chunk_scan<<<(BATCH * DMODEL * DSTATE) / 256, 256, 0, stream>>>(E, Hin, lam, aph, C, L);
    ssm_output<<<BATCH * C, 64, 0, stream>>>(x, lam, aph, Bre, Bim, Cre, Cim, Dd, Hin, y, C, L);
}

// Round 2
// 170.270 us; speedup vs baseline: 1.0523x; 1.0523x over previous
//
#include <hip/hip_runtime.h>
#include <math.h>

#define BATCH  8
#define SEQ    8192
#define DMODEL 256
#define DSTATE 2
#define CHUNKS 256   // C
#define CLEN   32    // L = SEQ / C

// ---------------------------------------------------------------------------
// Layouts:
//   x  : [B][T][D] fp32
//   params (log_a_mag, a_phase, B_re, B_im, C_re, C_im): [D][S] fp32 (S=2)
//   E / Hin workspace: [B][C][64][16] floats = [B][C][1024]
//       per (b, c): lane d4 = d/4 owns 16 floats: j=0..3 -> (s0re, s0im, s1re, s1im)
//       slot r = d4*8 + j*2 + s  ->  float2 at offset 2r within the 1024 block.
//   y  : [B][T][D] fp32
// Recurrence: h[t] = a * h[t-1] + Bc * x[t],  a = e^{lm} (cos ph + i sin ph)
// y[t,d] = sum_s Re(C * h) + D_diag * x
// ---------------------------------------------------------------------------

// Kernel 1: per-chunk local end state (zero initial condition).
// grid = BATCH * CHUNKS blocks, 64 threads. block -> (b, c); lane -> d4 (4 d's).
__global__ void ssm_chunk_state(const float* __restrict__ x,
                                const float* __restrict__ lam,
                                const float* __restrict__ aph,
                                const float* __restrict__ Bre,
                                const float* __restrict__ Bim,
                                float* __restrict__ E) {
    const int lane = threadIdx.x;           // 0..63
    const int bid  = blockIdx.x;            // b*C + c
    const int b = bid / CHUNKS;
    const int c = bid % CHUNKS;
    const int d0 = lane * 4;

    float ar[4][2], ai[4][2], br[4][2], bi[4][2];
#pragma unroll
    for (int j = 0; j < 4; ++j) {
        const int d = d0 + j;
#pragma unroll
        for (int s = 0; s < 2; ++s) {
            const float lm = lam[d * 2 + s];
            const float ph = aph[d * 2 + s];
            const float m  = expf(lm);
            ar[j][s] = m * cosf(ph);
            ai[j][s] = m * sinf(ph);
            br[j][s] = Bre[d * 2 + s];
            bi[j][s] = Bim[d * 2 + s];
        }
    }

    float hr[4][2] = {}, hi[4][2] = {};

    const float* xp = x + ((size_t)b * SEQ + (size_t)c * CLEN) * DMODEL + d0;
#pragma unroll 4
    for (int t = 0; t < CLEN; ++t) {
        const float4 xv = *reinterpret_cast<const float4*>(xp + (size_t)t * DMODEL);
        const float xj[4] = {xv.x, xv.y, xv.z, xv.w};
#pragma unroll
        for (int j = 0; j < 4; ++j) {
#pragma unroll
            for (int s = 0; s < 2; ++s) {
                const float nr = fmaf(ar[j][s], hr[j][s],
                                 fmaf(-ai[j][s], hi[j][s], br[j][s] * xj[j]));
                const float ni = fmaf(ar[j][s], hi[j][s],
                                 fmaf( ai[j][s], hr[j][s], bi[j][s] * xj[j]));
                hr[j][s] = nr;
                hi[j][s] = ni;
            }
        }
    }

    float* ep = E + ((size_t)(b * CHUNKS + c) * 64 + lane) * 16;
#pragma unroll
    for (int j = 0; j < 4; ++j) {
        float4 v;
        v.x = hr[j][0]; v.y = hi[j][0];
        v.z = hr[j][1]; v.w = hi[j][1];
        reinterpret_cast<float4*>(ep)[j] = v;
    }
}

// Kernel 2: wave-parallel scan over chunks. One wave per (b, d, s) scan;
// lane l owns chunks 4l..4l+3. Linear recurrence with uniform multiplier
// A = a^CLEN, so Kogge-Stone step multiplier is exactly A^(4k) (fp64).
// grid = 1024 blocks x 256 threads = 4096 waves = BATCH * 512 slots.
__global__ void ssm_chunk_scan(const float* __restrict__ E,
                               float* __restrict__ Hin,
                               const float* __restrict__ lam,
                               const float* __restrict__ aph) {
    const int lane = threadIdx.x & 63;
    const int g = blockIdx.x * 4 + (threadIdx.x >> 6);  // wave id 0..4095
    const int b = g >> 9;
    const int r = g & 511;                               // d4*8 + j*2 + s
    const int d = (r >> 3) * 4 + ((r >> 1) & 3);
    const int s = r & 1;

    const double lm = (double)lam[d * 2 + s];
    const double ph = (double)aph[d * 2 + s];
    // A = a^CLEN
    {
    }
    const double mL = exp(lm * (double)CLEN);
    const double pL = ph * (double)CLEN;
    const float Ar = (float)(mL * cos(pL));
    const float Ai = (float)(mL * sin(pL));

    const size_t base = (size_t)b * CHUNKS * 1024 + (size_t)r * 2;

    float2 e[4];
#pragma unroll
    for (int i = 0; i < 4; ++i) {
        const int c = lane * 4 + i;
        e[i] = *reinterpret_cast<const float2*>(E + base + (size_t)c * 1024);
    }

    // local group aggregate: v = A^3 e0 + A^2 e1 + A e2 + e3
    float vr = e[0].x, vi = e[0].y;
#pragma unroll
    for (int i = 1; i < 4; ++i) {
        const float nr = fmaf(Ar, vr, fmaf(-Ai, vi, e[i].x));
        const float ni = fmaf(Ar, vi, fmaf( Ai, vr, e[i].y));
        vr = nr; vi = ni;
    }

    // Kogge-Stone inclusive scan over 64 lane-groups, multiplier W_k = A^(4k)
#pragma unroll
    for (int st = 0; st < 6; ++st) {
        const int k = 1 << st;
        const double n = (double)CLEN * 4.0 * (double)k;
        const double mm = exp(lm * n);
        const double pp = ph * n;
        const float Wr = (float)(mm * cos(pp));
        const float Wi = (float)(mm * sin(pp));
        const float ur = __shfl_up(vr, (unsigned)k);
        const float ui = __shfl_up(vi, (unsigned)k);
        if (lane >= k) {
            vr = fmaf(Wr, ur, fmaf(-Wi, ui, vr));
            vi = fmaf(Wr, ui, fmaf( Wi, ur, vi));
        }
    }

    // exclusive across lane-groups: P_{4l-1} = Hin(4l)
    float pr = __shfl_up(vr, 1);
    float pi = __shfl_up(vi, 1);
    if (lane == 0) { pr = 0.f; pi = 0.f; }

#pragma unroll
    for (int i = 0; i < 4; ++i) {
        const int c = lane * 4 + i;
        *reinterpret_cast<float2*>(Hin + base + (size_t)c * 1024) = make_float2(pr, pi);
        // P_c = A * P_{c-1} + E_c  -> Hin(c+1)
        const float nr = fmaf(Ar, pr, fmaf(-Ai, pi, e[i].x));
        const float ni = fmaf(Ar, pi, fmaf( Ai, pr, e[i].y));
        pr = nr; pi = ni;
    }
}

// Kernel 3: re-run local recurrence seeded from Hin; fuse output projection.
__global__ void ssm_output(const float* __restrict__ x,
                           const float* __restrict__ lam,
                           const float* __restrict__ aph,
                           const float* __restrict__ Bre,
                           const float* __restrict__ Bim,
                           const float* __restrict__ Cre,
                           const float* __restrict__ Cim,
                           const float* __restrict__ Dd,
                           const float* __restrict__ Hin,
                           float* __restrict__ y) {
    const int lane = threadIdx.x;
    const int bid  = blockIdx.x;
    const int b = bid / CHUNKS;
    const int c = bid % CHUNKS;
    const int d0 = lane * 4;

    float ar[4][2], ai[4][2], br[4][2], bi[4][2], cr[4][2], ci[4][2], dd[4];
#pragma unroll
    for (int j = 0; j < 4; ++j) {
        const int d = d0 + j;
        dd[j] = Dd[d];
#pragma unroll
        for (int s = 0; s < 2; ++s) {
            const float lm = lam[d * 2 + s];
            const float ph = aph[d * 2 + s];
            const float m  = expf(lm);
            ar[j][s] = m * cosf(ph);
            ai[j][s] = m * sinf(ph);
            br[j][s] = Bre[d * 2 + s];
            bi[j][s] = Bim[d * 2 + s];
            cr[j][s] = Cre[d * 2 + s];
            ci[j][s] = Cim[d * 2 + s];
        }
    }

    float hr[4][2], hi[4][2];
    const float* hp = Hin + ((size_t)(b * CHUNKS + c) * 64 + lane) * 16;
#pragma unroll
    for (int j = 0; j < 4; ++j) {
        const float4 v = reinterpret_cast<const float4*>(hp)[j];
        hr[j][0] = v.x; hi[j][0] = v.y;
        hr[j][1] = v.z; hi[j][1] = v.w;
    }

    const size_t tbase = ((size_t)b * SEQ + (size_t)c * CLEN) * DMODEL + d0;
    const float* xp = x + tbase;
    float* yp = y + tbase;
#pragma unroll 4
    for (int t = 0; t < CLEN; ++t) {
        const float4 xv = *reinterpret_cast<const float4*>(xp + (size_t)t * DMODEL);
        const float xj[4] = {xv.x, xv.y, xv.z, xv.w};
        float yj[4];
#pragma unroll
        for (int j = 0; j < 4; ++j) {
            float acc = dd[j] * xj[j];
#pragma unroll
            for (int s = 0; s < 2; ++s) {
                const float nr = fmaf(ar[j][s], hr[j][s],
                                 fmaf(-ai[j][s], hi[j][s], br[j][s] * xj[j]));
                const float ni = fmaf(ar[j][s], hi[j][s],
                                 fmaf( ai[j][s], hr[j][s], bi[j][s] * xj[j]));
                hr[j][s] = nr;
                hi[j][s] = ni;
                acc = fmaf(cr[j][s], nr, acc);
                acc = fmaf(-ci[j][s], ni, acc);
            }
            yj[j] = acc;
        }
        float4 yv;
        yv.x = yj[0]; yv.y = yj[1]; yv.z = yj[2]; yv.w = yj[3];
        *reinterpret_cast<float4*>(yp + (size_t)t * DMODEL) = yv;
    }
}

extern "C" void kernel_launch(void* const* d_in, const int* in_sizes, int n_in,
                              void* d_out, int out_size, void* d_ws, size_t ws_size,
                              hipStream_t stream) {
    const float* x   = (const float*)d_in[0];
    const float* lam = (const float*)d_in[1];
    const float* aph = (const float*)d_in[2];
    const float* Bre = (const float*)d_in[3];
    const float* Bim = (const float*)d_in[4];
    const float* Cre = (const float*)d_in[5];
    const float* Cim = (const float*)d_in[6];
    const float* Dd  = (const float*)d_in[7];
    float* y = (float*)d_out;

    float* E   = (float*)d_ws;                                  // 8 MB
    float* Hin = E + (size_t)BATCH * CHUNKS * 1024;             // 8 MB

    ssm_chunk_state<<<BATCH * CHUNKS, 64, 0, stream>>>(x, lam, aph, Bre, Bim, E);
    ssm_chunk_scan<<<(BATCH * 512) / 4, 256, 0, stream>>>(E, Hin, lam, aph);
    ssm_output<<<BATCH * CHUNKS, 64, 0, stream>>>(x, lam, aph, Bre, Bim, Cre, Cim, Dd, Hin, y);
}